// Round 13
// baseline (257.197 us; speedup 1.0000x reference)
//
#include <hip/hip_runtime.h>
#include <hip/hip_bf16.h>

// GraphSAGE 2-layer forward: project-then-aggregate, bf16-MFMA GEMMs.
// Round 23: halve gemm0's x bytes. r11 vs r12 proved gemm0 is bound by
// delivered memory bytes (~2.3 TB/s), not CUs/pipelining/barriers. So:
//  - NEW xconv_k: transpose-convert x [1000][50000] fp32 -> xb [50176][1024]
//    bf16 (RNE, same rounding packx used -> identical numerics). k>=1000 and
//    cells>=N zero-padded. ~300MB streaming pass, leaves xb L3-hot.
//  - gemm0 rebuilt: A staged via global_load_lds from xb (row-major [cell][k]
//    = linear LDS, no packx/cvt, ~50 VGPR freed). LDS 128B-row 16-way bank
//    conflict fixed by pre-swizzled glds SOURCE slot ((l&7)^((l>>3)&7)) +
//    XOR'd read col ((lr&7)<<4) — the same both-sides swizzle h1b/gemm1 use.
//    128-cell tiles, 4 waves, 391 blocks at bounds(256,2) = 2 blocks/CU so
//    sibling blocks hide each other's barrier drains. x bytes: 200->100MB.
// Everything else frozen at r12 state. 8 dispatches.

#define IN_DIM 1000

typedef __attribute__((ext_vector_type(8))) short bf16x8;
typedef __attribute__((ext_vector_type(4))) float f32x4;

static __device__ __forceinline__ unsigned int f2bf(float f){
  union { float f; unsigned int u; } v; v.f = f;
  return (v.u + 0x7fffu + ((v.u >> 16) & 1u)) >> 16;   // RNE
}
static __device__ __forceinline__ float bl(unsigned v){
  union { unsigned u; float f; } t; t.u = v << 16; return t.f;
}
static __device__ __forceinline__ float bh(unsigned v){
  union { unsigned u; float f; } t; t.u = v & 0xFFFF0000u; return t.f;
}
static __device__ __forceinline__ void glds16(const void* g, void* lds){
  __builtin_amdgcn_global_load_lds(
      (const __attribute__((address_space(1))) unsigned int*)g,
      (__attribute__((address_space(3))) unsigned int*)lds, 16, 0, 0);
}

// -------- prep: B0img (fragment layout) + B1img (row layout) + zeroing -------
__global__ void prep_k(const float* __restrict__ Wl0, const float* __restrict__ Wr0,
                       const float* __restrict__ Wl1, const float* __restrict__ Wr1,
                       unsigned short* __restrict__ img0,
                       unsigned short* __restrict__ img1, int total0, int total1,
                       int* __restrict__ zptr, int zn){
  int idx = blockIdx.x*256 + threadIdx.x;
  if (idx < total0){
    int j  = idx & 7;
    int l  = (idx >> 3) & 63;
    int ks = (idx >> 9) & 1;
    int n  = (idx >> 10) & 3;
    int w  = (idx >> 12) & 3;
    int s  = idx >> 14;
    int row = w*64 + n*16 + (l & 15);
    int k   = s*64 + ks*32 + (l >> 4)*8 + j;
    float val = 0.f;
    if (k < IN_DIM)
      val = (row < 128) ? Wl0[(size_t)row*IN_DIM + k] : Wr0[(size_t)(row-128)*IN_DIM + k];
    img0[idx] = (unsigned short)f2bf(val);
    return;
  }
  idx -= total0;
  if (idx < total1){
    int s   = idx / (256*72);
    int rem = idx % (256*72);
    int n   = rem / 72;
    int e   = rem % 72;
    float val = 0.f;
    if (e < 64){
      int k = s*64 + e;
      if (k < 128) val = (n < 128) ? Wl1[(size_t)n*128 + k] : Wr1[(size_t)(n-128)*128 + k];
    }
    img1[idx] = (unsigned short)f2bf(val);
    return;
  }
  idx -= total1;
  if (idx < zn) zptr[idx] = 0;
}

// -------- xconv: transpose x [Ka][N] fp32 -> xb [>=50176][1024] bf16 ---------
// 64x64 tiles through LDS. k>=Ka and cells>=N write 0 (zero-pad).
__global__ void xconv_k(const float* __restrict__ x, unsigned short* __restrict__ xb,
                        int N, int Ka){
  __shared__ unsigned short t[64][80];          // 80-pad: 160B rows, 16B-aligned
  int bid = blockIdx.x;
  int kt = bid & 15;                            // 16 k-tiles (K padded to 1024)
  int ct = bid >> 4;                            // cell tiles
  int k0 = kt*64, c0 = ct*64;
  int tid = threadIdx.x;
  int cl  = (tid & 15)*4;                       // cell_local base (4 cells)
  int kl0 = tid >> 4;                           // 0..15
  #pragma unroll
  for (int r = 0; r < 4; ++r){
    int kl = r*16 + kl0;
    int k  = k0 + kl;
    int c  = c0 + cl;
    float4 v = make_float4(0.f,0.f,0.f,0.f);
    if (k < Ka && c < N) v = *(const float4*)&x[(size_t)k*N + c];
    t[cl+0][kl] = (unsigned short)f2bf(v.x);
    t[cl+1][kl] = (unsigned short)f2bf(v.y);
    t[cl+2][kl] = (unsigned short)f2bf(v.z);
    t[cl+3][kl] = (unsigned short)f2bf(v.w);
  }
  __syncthreads();
  #pragma unroll
  for (int it = 0; it < 2; ++it){
    int u = it*256 + tid;
    int cell = u >> 3, g = u & 7;               // 16B unit g within 128B chunk
    uint4 w = *(const uint4*)&t[cell][g*8];
    *(uint4*)((char*)xb + (size_t)(c0 + cell)*2048 + (size_t)kt*128 + g*16) = w;
  }
}

// -------- scan1: block-local excl prescan + inv; last block scans bsum ------
__global__ void scan1_k(const int* __restrict__ cnt, int* __restrict__ rowp,
                        float* __restrict__ inv, int* __restrict__ bsum,
                        int* __restrict__ ticket, int N, int nb){
  __shared__ int wt[4];
  __shared__ int lastS;
  int bid = blockIdx.x;
  int i = bid*256 + threadIdx.x;
  int lane = threadIdx.x & 63, wid = threadIdx.x >> 6;
  int v = (i < N) ? cnt[i] : 0;
  int sc = v;
  #pragma unroll
  for (int off = 1; off < 64; off <<= 1){
    int o = __shfl_up(sc, off);
    if (lane >= off) sc += o;
  }
  if (lane == 63) wt[wid] = sc;
  __syncthreads();
  if (threadIdx.x == 0){
    int a = 0;
    #pragma unroll
    for (int j = 0; j < 4; ++j){ int t = wt[j]; wt[j] = a; a += t; }
    bsum[bid] = a;
    if (bid == nb-1 && (N & 255)) rowp[N] = a;
  }
  __syncthreads();
  if (i < N){
    rowp[i] = wt[wid] + sc - v;
    inv[i]  = 1.0f / fmaxf((float)v, 1.0f);
  }
  __threadfence();
  if (threadIdx.x == 0){
    int t = __hip_atomic_fetch_add(ticket, 1, __ATOMIC_ACQ_REL, __HIP_MEMORY_SCOPE_AGENT);
    lastS = (t == (int)gridDim.x - 1);
  }
  __syncthreads();
  if (lastS){
    __threadfence();
    int t2 = threadIdx.x;
    int bv = (t2 < nb) ? __hip_atomic_load(&bsum[t2], __ATOMIC_RELAXED,
                                           __HIP_MEMORY_SCOPE_AGENT) : 0;
    int sc2 = bv;
    #pragma unroll
    for (int off = 1; off < 64; off <<= 1){
      int o = __shfl_up(sc2, off);
      if (lane >= off) sc2 += o;
    }
    __syncthreads();
    if (lane == 63) wt[wid] = sc2;
    __syncthreads();
    if (t2 == 0){
      int a = 0;
      #pragma unroll
      for (int j = 0; j < 4; ++j){ int t = wt[j]; wt[j] = a; a += t; }
      bsum[nb] = a;
      if (!(N & 255)) rowp[N] = 0;
    }
    __syncthreads();
    if (t2 < nb) bsum[t2] = wt[wid] + sc2 - bv;
  }
}

__global__ void fill_col_k(const int* __restrict__ ei, int E,
                           const int* __restrict__ rowp, const int* __restrict__ bsum,
                           int* __restrict__ pos, int* __restrict__ col){
  int e = blockIdx.x*blockDim.x + threadIdx.x;
  if (e < E){
    int src = ei[e];
    int dst = ei[(size_t)E + e];
    int p = atomicAdd(&pos[dst], 1);
    col[rowp[dst] + bsum[dst >> 8] + p] = src;
  }
}

// ------- GEMM0: bf16 xb, glds A-staging, 128-cell tiles, 2/CU + count tail ---
// bid < nblk: gemm tile (128 cells x 256 outputs), A from xb via glds16 with
// source-side slot swizzle; LDS read XORs ((lr&7)<<4) -> ~2-way conflicts.
// bid >= nblk: edge-count blocks (backfill).
__global__ __launch_bounds__(256, 2) void gemm0_count_k(
    const unsigned short* __restrict__ xb, const unsigned short* __restrict__ B0img,
    unsigned short* __restrict__ ybl, unsigned short* __restrict__ ybr,
    int N, int nsteps, int nblk,
    const int* __restrict__ ei, int E, int* __restrict__ cnt){
  if ((int)blockIdx.x >= nblk){                 // tail: edge counting
    int idx = ((int)blockIdx.x - nblk)*256 + threadIdx.x;
    if (idx < E) atomicAdd(&cnt[ei[(size_t)E + idx]], 1);
    return;
  }
  __shared__ char AsB[128*128];                 // 16 KB: 128 cells x 64k bf16
  const int tid = threadIdx.x;
  const int c0  = blockIdx.x * 128;
  const int l   = tid & 63, wid = tid >> 6;     // 4 waves = 4 n-quadrants
  const int nw  = wid * 64;
  const int lr  = l & 15, lq = l >> 4;
  const int arow  = l >> 3;                     // glds: row within 8-row group
  const int aslot = ((l & 7) ^ arow) << 4;      // pre-swizzled source slot

  f32x4 acc[8][4];
  #pragma unroll
  for (int m=0;m<8;++m)
    #pragma unroll
    for (int n=0;n<4;++n) acc[m][n] = (f32x4){0.f,0.f,0.f,0.f};

  // per-wave fragment base: (((s*4+wid)*4+n)*2+ks)*1024 + l*16 bytes
  const char* bbase = (const char*)B0img + (size_t)wid*8192 + (size_t)l*16;
  bf16x8 bf[8];

  auto loadB = [&](int s){
    const char* p = bbase + (size_t)s*32768;
    #pragma unroll
    for (int n = 0; n < 4; ++n)
      #pragma unroll
      for (int ks = 0; ks < 2; ++ks)
        bf[n*2+ks] = *(const bf16x8*)(p + n*2048 + ks*1024);
  };
  auto domfma = [&](){
    #pragma unroll
    for (int ks = 0; ks < 2; ++ks){
      bf16x8 a[8];
      #pragma unroll
      for (int m = 0; m < 8; ++m)
        a[m] = *(const bf16x8*)&AsB[(m*16 + lr)*128 + ((ks*64 + lq*16) ^ ((lr & 7) << 4))];
      #pragma unroll
      for (int n = 0; n < 4; ++n)
        #pragma unroll
        for (int m = 0; m < 8; ++m)
          acc[m][n] = __builtin_amdgcn_mfma_f32_16x16x32_bf16(a[m], bf[n*2+ks], acc[m][n], 0, 0, 0);
    }
  };

  for (int s = 0; s < nsteps; ++s){
    if (s) __syncthreads();            // AsB reads (s-1) done
    #pragma unroll
    for (int i = 0; i < 4; ++i){       // stage A: 32 rows per wave
      int rbase = wid*32 + i*8;
      glds16((const char*)xb + (size_t)(c0 + rbase + arow)*2048 + (size_t)s*128 + aslot,
             &AsB[rbase*128]);
    }
    loadB(s);                          // L2 frag loads, consumed this step
    __syncthreads();                   // drains vmcnt: A in LDS
    domfma();
  }

  unsigned short* op = (nw < 128) ? ybl : ybr;
  const int       nc = (nw < 128) ? nw : nw - 128;
  #pragma unroll
  for (int m = 0; m < 8; ++m){
    int rbase = c0 + m*16 + lq*4;
    #pragma unroll
    for (int q = 0; q < 4; ++q){
      int r2 = rbase + q;
      if (r2 < N){
        #pragma unroll
        for (int n = 0; n < 4; ++n)
          op[(size_t)r2*128 + nc + n*16 + lr] = (unsigned short)f2bf(acc[m][n][q]);
      }
    }
  }
}

// ---------------- GEMM1: 128-row tiles (straggler fix), glds staging ---------
__global__ __launch_bounds__(256, 2) void gemm1_k(
    const void* __restrict__ Ap, const unsigned short* __restrict__ Bimg,
    unsigned short* __restrict__ ybl, unsigned short* __restrict__ ybr,
    int N, int nsteps){
  __shared__ char AsB[128*128];                 // 16 KB
  __shared__ char BsB[36864];                   // 36 KB
  const int tid = threadIdx.x;
  const int c0  = blockIdx.x * 128;
  const int l   = tid & 63, wid = tid >> 6;
  const int nw  = wid * 64;
  const int lr  = l & 15, lq = l >> 4;

  f32x4 acc[8][4];
  #pragma unroll
  for (int m=0;m<8;++m)
    #pragma unroll
    for (int n=0;n<4;++n) acc[m][n] = (f32x4){0.f,0.f,0.f,0.f};

  const char* h1b = (const char*)Ap;

  for (int s = 0; s < nsteps; ++s){
    if (s) __syncthreads();
    {
      const char* bsrc = (const char*)Bimg + (size_t)s*36864;
      #pragma unroll
      for (int i = 0; i < 9; ++i){
        int chunk = i*256 + tid;
        glds16(bsrc + (size_t)chunk*16, &BsB[(i*256 + wid*64)*16]);
      }
    }
    #pragma unroll
    for (int i = 0; i < 4; ++i){                // 128 rows x 128B per step
      int chunk = i*256 + tid;
      int row = chunk >> 3, cb = (chunk & 7)*16;
      glds16(h1b + (size_t)(c0 + row)*256 + s*128 + cb,
             &AsB[(i*256 + wid*64)*16]);
    }
    __syncthreads();                            // glds -> full drain required
    #pragma unroll
    for (int ks = 0; ks < 2; ++ks){
      bf16x8 a[8];
      #pragma unroll
      for (int m = 0; m < 8; ++m){
        int row = m*16 + lr;
        int colb = (ks*64 + lq*16) ^ ((row & 7) << 4);
        a[m] = *(const bf16x8*)&AsB[row*128 + colb];
      }
      #pragma unroll
      for (int n = 0; n < 4; ++n){
        bf16x8 b = *(const bf16x8*)&BsB[(nw + n*16 + lr)*144 + ks*64 + lq*16];
        #pragma unroll
        for (int m = 0; m < 8; ++m)
          acc[m][n] = __builtin_amdgcn_mfma_f32_16x16x32_bf16(a[m], b, acc[m][n], 0, 0, 0);
      }
    }
  }
  unsigned short* op  = (nw < 128) ? ybl : ybr;
  const int       nc  = (nw < 128) ? nw : nw - 128;
  #pragma unroll
  for (int m = 0; m < 8; ++m){
    int rbase = c0 + m*16 + lq*4;
    #pragma unroll
    for (int q = 0; q < 4; ++q){
      int r = rbase + q;
      if (r < N){
        #pragma unroll
        for (int n = 0; n < 4; ++n)
          op[(size_t)r*128 + nc + n*16 + lr] = (unsigned short)f2bf(acc[m][n][q]);
      }
    }
  }
}

// ------- aggregate: lane-parallel col fetch + 16-deep row gather -------------
template<int LAYER>
__global__ void aggregate_k(const unsigned short* __restrict__ ybl,
    const unsigned short* __restrict__ ybr,
    const int* __restrict__ rowp, const int* __restrict__ bsum,
    const int* __restrict__ col,
    const float* __restrict__ inv, const float* __restrict__ bias,
    void* __restrict__ outp, int N){
  int node = blockIdx.x*4 + (threadIdx.x >> 6);
  int l = threadIdx.x & 63;
  if (node >= N) return;
  int b = rowp[node]   + bsum[node >> 8];
  int e = rowp[node+1] + bsum[(node+1) >> 8];
  int f2 = l*2;
  const unsigned* yl = (const unsigned*)ybl;
  float s0=0.f,s1=0.f,t0=0.f,t1=0.f,u0=0.f,u1=0.f,w0=0.f,w1=0.f;
  for (int kb = b; kb < e; kb += 64){
    int rem = e - kb; if (rem > 64) rem = 64;
    int myc = (l < rem) ? col[kb + l] : 0;      // one coalesced col load
    for (int j = 0; j < rem; j += 16){
      unsigned a[16];
      #pragma unroll
      for (int jj = 0; jj < 16; ++jj){
        int src = __shfl(myc, j + jj);          // broadcast (VALU/LDS, cheap)
        unsigned v = yl[(size_t)src*64 + l];    // gather, 16 in flight
        a[jj] = (j + jj < rem) ? v : 0u;
      }
      #pragma unroll
      for (int h = 0; h < 2; ++h){
        s0 += bl(a[h*8+0]); s1 += bh(a[h*8+0]); t0 += bl(a[h*8+1]); t1 += bh(a[h*8+1]);
        u0 += bl(a[h*8+2]); u1 += bh(a[h*8+2]); w0 += bl(a[h*8+3]); w1 += bh(a[h*8+3]);
        s0 += bl(a[h*8+4]); s1 += bh(a[h*8+4]); t0 += bl(a[h*8+5]); t1 += bh(a[h*8+5]);
        u0 += bl(a[h*8+6]); u1 += bh(a[h*8+6]); w0 += bl(a[h*8+7]); w1 += bh(a[h*8+7]);
      }
    }
  }
  s0 = (s0 + t0) + (u0 + w0);
  s1 = (s1 + t1) + (u1 + w1);
  unsigned vs = *(const unsigned*)&ybr[(size_t)node*128 + f2];
  float iv = inv[node];
  float r0 = s0*iv + bias[f2]   + bl(vs);
  float r1 = s1*iv + bias[f2+1] + bh(vs);
  r0 = (r0 > 0.f) ? r0 : expm1f(r0);
  r1 = (r1 > 0.f) ? r1 : expm1f(r1);
  if (LAYER == 0){
    int sf = f2 >> 6, fo = f2 & 63, g = fo >> 3;
    size_t byte = (size_t)node*256 + (size_t)(sf*128 + ((g ^ (node & 7)) << 4) + (fo & 7)*2);
    *(unsigned*)((char*)outp + byte) = f2bf(r0) | (f2bf(r1) << 16);
  } else {
    *(float2*)((float*)outp + (size_t)node*128 + f2) = make_float2(r0, r1);
  }
}

static inline size_t align_up(size_t v, size_t a){ return (v + a - 1) & ~(a - 1); }

extern "C" void kernel_launch(void* const* d_in, const int* in_sizes, int n_in,
                              void* d_out, int out_size, void* d_ws, size_t ws_size,
                              hipStream_t stream) {
  const float* x   = (const float*)d_in[0];
  const int*   ei  = (const int*)d_in[1];      // harness delivers int32
  const float* Wl0 = (const float*)d_in[2];
  const float* bl0 = (const float*)d_in[3];
  const float* Wr0 = (const float*)d_in[4];
  const float* Wl1 = (const float*)d_in[5];
  const float* bl1 = (const float*)d_in[6];
  const float* Wr1 = (const float*)d_in[7];

  int N = in_sizes[0] / IN_DIM;   // 50000
  int E = in_sizes[1] / 2;        // 800000

  const int NS0 = 16;             // K padded to 1024
  const int NS1 = 2;              // K = 128
  int nsb = (N + 255) / 256;      // 196 (<=256 for inline bsum scan)

  char* base = (char*)d_ws;
  size_t off = 0;
  unsigned short* ybl = (unsigned short*)(base + off); off = align_up(off + (size_t)N*128*2, 256);
  unsigned short* ybr = (unsigned short*)(base + off); off = align_up(off + (size_t)N*128*2, 256);
  float* inv  = (float*)(base + off); off = align_up(off + (size_t)N*4, 256);
  int*   cnt  = (int*)  (base + off); off = align_up(off + (size_t)N*8 + 256, 256); // cnt+pos+ticket
  int*   pos  = cnt + N;
  int*   ticket = cnt + 2*N;
  int*   rowp = (int*)  (base + off); off = align_up(off + (size_t)(N+1)*4, 256);
  int*   bsum = (int*)  (base + off); off = align_up(off + (size_t)(nsb+1)*4, 256);
  int*   col  = (int*)  (base + off); off = align_up(off + (size_t)E*4, 256);
  unsigned short* B0img = (unsigned short*)(base + off); off = align_up(off + (size_t)524288*2, 256);
  unsigned short* B1img = (unsigned short*)(base + off); off = align_up(off + (size_t)NS1*18432*2, 256);
  unsigned short* xb    = (unsigned short*)(base + off); off = align_up(off + (size_t)50176*1024*2, 256);
  void* h1b = d_out;              // bf16 swizzled h1 (12.8 MB) inside d_out
  (void)ws_size; (void)n_in; (void)out_size;

  int t0n = 524288, t1n = NS1*18432;
  int zn  = 2*N + 64;             // cnt + pos + ticket (+pad), zeroed by prep_k
  prep_k<<<(t0n+t1n+zn+255)/256, 256, 0, stream>>>(Wl0, Wr0, Wl1, Wr1,
                                                   B0img, B1img, t0n, t1n,
                                                   cnt, zn);

  int ctiles = (50176 + 63) / 64; // 784 cell tiles (covers all gemm0 reads)
  xconv_k<<<16*ctiles, 256, 0, stream>>>(x, xb, N, IN_DIM);

  int nblk = (N + 127) / 128;     // 391 gemm0 tiles (128 cells each)
  int cblk = (E + 255) / 256;     // 3125
  int ablk = (N + 3) / 4;         // 12500

  // gemm0 + edge-count in one dispatch; counts are tail bids (backfill overlap)
  gemm0_count_k<<<nblk + cblk, 256, 0, stream>>>(xb, B0img, ybl, ybr, N,
                                                 NS0, nblk, ei, E, cnt);
  scan1_k<<<nsb, 256, 0, stream>>>(cnt, rowp, inv, bsum, ticket, N, nsb);
  fill_col_k<<<(E+255)/256, 256, 0, stream>>>(ei, E, rowp, bsum, pos, col);
  aggregate_k<0><<<ablk, 256, 0, stream>>>(ybl, ybr, rowp, bsum, col, inv, bl0, h1b, N);

  // layer 1 (ybl/ybr reused; agg0 fully drained first; 128-row tiles)
  gemm1_k<<<nblk, 256, 0, stream>>>(h1b, B1img, ybl, ybr, N, NS1);
  aggregate_k<1><<<ablk, 256, 0, stream>>>(ybl, ybr, rowp, bsum, col, inv, bl1, d_out, N);
}

// Round 14
// 208.072 us; speedup vs baseline: 1.2361x; 1.2361x over previous
//
#include <hip/hip_runtime.h>
#include <hip/hip_bf16.h>

// GraphSAGE 2-layer forward: project-then-aggregate, bf16-MFMA GEMMs.
// Round 24: revert r23's xconv (transpose pass cost ~100us > gain). Base = r12
// (best, 210.2us). One change: gemm0's B fragments staged through LDS.
// Model: r12 gemm0 delivers A 64KB + B 64KB = 128KB/CU/step over 5.6us
// = 10.9 B/cy/CU == the m13 achievable memory rate (6.29TB/s / 256CU / 2.4GHz).
// gemm0 is AT the vmem delivery ceiling and HALF the bytes are B reloads
// (32KB unique, x2 mh-wave duplication). Fix: glds-stage B once per block per
// step (32KB, double-buffered, staged one step ahead); domfma ds_reads b.
// vmem/step: 128KB -> 96KB (-25%). No manual vmcnt needed: glds B(s+1) is
// issued BEFORE packx consumes xv(s), so the compiler's vmcnt wait for xv(s)
// (newer than glds B(s)) forces B(s) landed before the barrier; a zero-cost
// memory-clobber pins the issue order. LDS 36+64=100KB, 1 block/CU (as r12).
// Everything else frozen at r12. 7 dispatches.

#define IN_DIM 1000

#define KBARRIER() asm volatile("s_waitcnt lgkmcnt(0)\n\ts_barrier" ::: "memory")

typedef __attribute__((ext_vector_type(8))) short bf16x8;
typedef __attribute__((ext_vector_type(4))) float f32x4;

static __device__ __forceinline__ unsigned int f2bf(float f){
  union { float f; unsigned int u; } v; v.f = f;
  return (v.u + 0x7fffu + ((v.u >> 16) & 1u)) >> 16;   // RNE
}
static __device__ __forceinline__ float bl(unsigned v){
  union { unsigned u; float f; } t; t.u = v << 16; return t.f;
}
static __device__ __forceinline__ float bh(unsigned v){
  union { unsigned u; float f; } t; t.u = v & 0xFFFF0000u; return t.f;
}
static __device__ __forceinline__ void glds16(const void* g, void* lds){
  __builtin_amdgcn_global_load_lds(
      (const __attribute__((address_space(1))) unsigned int*)g,
      (__attribute__((address_space(3))) unsigned int*)lds, 16, 0, 0);
}

// -------- prep: B0img (fragment layout) + B1img (row layout) + zeroing -------
__global__ void prep_k(const float* __restrict__ Wl0, const float* __restrict__ Wr0,
                       const float* __restrict__ Wl1, const float* __restrict__ Wr1,
                       unsigned short* __restrict__ img0,
                       unsigned short* __restrict__ img1, int total0, int total1,
                       int* __restrict__ zptr, int zn){
  int idx = blockIdx.x*256 + threadIdx.x;
  if (idx < total0){
    int j  = idx & 7;
    int l  = (idx >> 3) & 63;
    int ks = (idx >> 9) & 1;
    int n  = (idx >> 10) & 3;
    int w  = (idx >> 12) & 3;
    int s  = idx >> 14;
    int row = w*64 + n*16 + (l & 15);
    int k   = s*64 + ks*32 + (l >> 4)*8 + j;
    float val = 0.f;
    if (k < IN_DIM)
      val = (row < 128) ? Wl0[(size_t)row*IN_DIM + k] : Wr0[(size_t)(row-128)*IN_DIM + k];
    img0[idx] = (unsigned short)f2bf(val);
    return;
  }
  idx -= total0;
  if (idx < total1){
    int s   = idx / (256*72);
    int rem = idx % (256*72);
    int n   = rem / 72;
    int e   = rem % 72;
    float val = 0.f;
    if (e < 64){
      int k = s*64 + e;
      if (k < 128) val = (n < 128) ? Wl1[(size_t)n*128 + k] : Wr1[(size_t)(n-128)*128 + k];
    }
    img1[idx] = (unsigned short)f2bf(val);
    return;
  }
  idx -= total1;
  if (idx < zn) zptr[idx] = 0;
}

// -------- scan1: block-local excl prescan + inv; last block scans bsum ------
__global__ void scan1_k(const int* __restrict__ cnt, int* __restrict__ rowp,
                        float* __restrict__ inv, int* __restrict__ bsum,
                        int* __restrict__ ticket, int N, int nb){
  __shared__ int wt[4];
  __shared__ int lastS;
  int bid = blockIdx.x;
  int i = bid*256 + threadIdx.x;
  int lane = threadIdx.x & 63, wid = threadIdx.x >> 6;
  int v = (i < N) ? cnt[i] : 0;
  int sc = v;
  #pragma unroll
  for (int off = 1; off < 64; off <<= 1){
    int o = __shfl_up(sc, off);
    if (lane >= off) sc += o;
  }
  if (lane == 63) wt[wid] = sc;
  __syncthreads();
  if (threadIdx.x == 0){
    int a = 0;
    #pragma unroll
    for (int j = 0; j < 4; ++j){ int t = wt[j]; wt[j] = a; a += t; }
    bsum[bid] = a;
    if (bid == nb-1 && (N & 255)) rowp[N] = a;
  }
  __syncthreads();
  if (i < N){
    rowp[i] = wt[wid] + sc - v;
    inv[i]  = 1.0f / fmaxf((float)v, 1.0f);
  }
  __threadfence();
  if (threadIdx.x == 0){
    int t = __hip_atomic_fetch_add(ticket, 1, __ATOMIC_ACQ_REL, __HIP_MEMORY_SCOPE_AGENT);
    lastS = (t == (int)gridDim.x - 1);
  }
  __syncthreads();
  if (lastS){
    __threadfence();
    int t2 = threadIdx.x;
    int bv = (t2 < nb) ? __hip_atomic_load(&bsum[t2], __ATOMIC_RELAXED,
                                           __HIP_MEMORY_SCOPE_AGENT) : 0;
    int sc2 = bv;
    #pragma unroll
    for (int off = 1; off < 64; off <<= 1){
      int o = __shfl_up(sc2, off);
      if (lane >= off) sc2 += o;
    }
    __syncthreads();
    if (lane == 63) wt[wid] = sc2;
    __syncthreads();
    if (t2 == 0){
      int a = 0;
      #pragma unroll
      for (int j = 0; j < 4; ++j){ int t = wt[j]; wt[j] = a; a += t; }
      bsum[nb] = a;
      if (!(N & 255)) rowp[N] = 0;
    }
    __syncthreads();
    if (t2 < nb) bsum[t2] = wt[wid] + sc2 - bv;
  }
}

__global__ void fill_col_k(const int* __restrict__ ei, int E,
                           const int* __restrict__ rowp, const int* __restrict__ bsum,
                           int* __restrict__ pos, int* __restrict__ col){
  int e = blockIdx.x*blockDim.x + threadIdx.x;
  if (e < E){
    int src = ei[e];
    int dst = ei[(size_t)E + e];
    int p = atomicAdd(&pos[dst], 1);
    col[rowp[dst] + bsum[dst >> 8] + p] = src;
  }
}

// ------- GEMM0: 256-cell tiles, 512 threads, LDS-staged B + count tail -------
// bid < nblk: gemm tile (256 cells x 256 outputs). 196 blocks, 1 block/CU
// (LDS 100KB). bid >= nblk: edge-count blocks (backfill).
// B per step: 32KB unique, glds-staged one step ahead into BsB[2] ping-pong;
// domfma ds_reads fragments (removes the 2x mh duplication + reg pressure).
__global__ __launch_bounds__(512, 2) void gemm0_count_k(
    const float* __restrict__ x, const unsigned short* __restrict__ B0img,
    unsigned short* __restrict__ ybl, unsigned short* __restrict__ ybr,
    int N, int Ka, int nsteps, int nblk,
    const int* __restrict__ ei, int E, int* __restrict__ cnt){
  if ((int)blockIdx.x >= nblk){                 // tail: edge counting
    int idx = ((int)blockIdx.x - nblk)*512 + threadIdx.x;
    if (idx < E) atomicAdd(&cnt[ei[(size_t)E + idx]], 1);
    return;
  }
  __shared__ char AsB[256*144];                 // 36 KB: 256 cells x 64 k bf16
  __shared__ char BsB[2][32768];                // 64 KB: B step ping-pong
  const int tid = threadIdx.x;
  const int c0  = blockIdx.x * 256;
  const int l   = tid & 63, wid = tid >> 6;     // 8 waves
  const int mh  = wid & 1;                      // cell half (0..127 / 128..255)
  const int nq  = wid >> 1;                     // n-quadrant (64 outs)
  const int nw  = nq * 64;
  const int lr  = l & 15, lq = l >> 4;
  const int c4  = l * 4;                        // pack: 4 cells per lane
  const int kg  = wid;                          // pack: wave's 8-k slice
  const int ce  = c0 + c4;
  const int ceff = (ce < N) ? ce : 0;           // N%4==0 -> ce<N covers ce..ce+3

  f32x4 acc[8][4];
  #pragma unroll
  for (int m=0;m<8;++m)
    #pragma unroll
    for (int n=0;n<4;++n) acc[m][n] = (f32x4){0.f,0.f,0.f,0.f};

  float2 xv0[8], xv1[8];                        // cells ce+0/1 and ce+2/3

  auto loadx = [&](int step){
    #pragma unroll
    for (int kk = 0; kk < 8; ++kk){
      int k = step*64 + kg*8 + kk;
      k = (k < Ka) ? k : (Ka - 1);              // B zero-pads k>=Ka
      const float* p = &x[(size_t)k*N + ceff];
      xv0[kk] = *(const float2*)p;
      xv1[kk] = *(const float2*)(p + 2);
    }
  };
  auto stageB = [&](int s, int buf){
    const char* src = (const char*)B0img + (size_t)s*32768;
    #pragma unroll
    for (int i = 0; i < 4; ++i){
      int chunk = i*512 + tid;                  // 16B unit
      glds16(src + (size_t)chunk*16, &BsB[buf][(i*512 + wid*64)*16]);
    }
  };
  auto packx = [&](){
    unsigned w0[4], w1[4], w2[4], w3[4];
    #pragma unroll
    for (int j = 0; j < 4; ++j){
      asm("v_cvt_pk_bf16_f32 %0, %1, %2" : "=v"(w0[j]) : "v"(xv0[2*j].x), "v"(xv0[2*j+1].x));
      asm("v_cvt_pk_bf16_f32 %0, %1, %2" : "=v"(w1[j]) : "v"(xv0[2*j].y), "v"(xv0[2*j+1].y));
      asm("v_cvt_pk_bf16_f32 %0, %1, %2" : "=v"(w2[j]) : "v"(xv1[2*j].x), "v"(xv1[2*j+1].x));
      asm("v_cvt_pk_bf16_f32 %0, %1, %2" : "=v"(w3[j]) : "v"(xv1[2*j].y), "v"(xv1[2*j+1].y));
    }
    *(uint4*)&AsB[(c4+0)*144 + kg*16] = make_uint4(w0[0],w0[1],w0[2],w0[3]);
    *(uint4*)&AsB[(c4+1)*144 + kg*16] = make_uint4(w1[0],w1[1],w1[2],w1[3]);
    *(uint4*)&AsB[(c4+2)*144 + kg*16] = make_uint4(w2[0],w2[1],w2[2],w2[3]);
    *(uint4*)&AsB[(c4+3)*144 + kg*16] = make_uint4(w3[0],w3[1],w3[2],w3[3]);
  };
  auto domfma = [&](int buf){
    #pragma unroll
    for (int ks = 0; ks < 2; ++ks){
      bf16x8 a[8];
      #pragma unroll
      for (int m = 0; m < 8; ++m)
        a[m] = *(const bf16x8*)&AsB[(mh*128 + m*16 + lr)*144 + ks*64 + lq*16];
      #pragma unroll
      for (int n = 0; n < 4; ++n){
        bf16x8 b = *(const bf16x8*)&BsB[buf][nq*8192 + (n*2+ks)*1024 + l*16];
        #pragma unroll
        for (int m = 0; m < 8; ++m)
          acc[m][n] = __builtin_amdgcn_mfma_f32_16x16x32_bf16(a[m], b, acc[m][n], 0, 0, 0);
      }
    }
  };

  stageB(0, 0);                        // B(0) older than xv(0) -> packx waits it
  loadx(0);
  for (int s = 0; s < nsteps; ++s){
    if (s) KBARRIER();                 // AsB/BsB[(s+1)&1] reads of s-1 done
    if (s + 1 < nsteps) stageB(s + 1, (s + 1) & 1);
    asm volatile("" ::: "memory");     // pin: glds B(s+1) issued before xv use
    packx();                           // compiler vmcnt wait -> B(s) landed
    if (s + 1 < nsteps) loadx(s + 1);  // HBM prefetch flies across barrier
    KBARRIER();                        // AsB/BsB visible (lgkm only)
    domfma(s & 1);
  }

  unsigned short* op = (nw < 128) ? ybl : ybr;
  const int       nc = (nw < 128) ? nw : nw - 128;
  #pragma unroll
  for (int m = 0; m < 8; ++m){
    int rbase = c0 + mh*128 + m*16 + lq*4;
    #pragma unroll
    for (int q = 0; q < 4; ++q){
      int r2 = rbase + q;
      if (r2 < N){
        #pragma unroll
        for (int n = 0; n < 4; ++n)
          op[(size_t)r2*128 + nc + n*16 + lr] = (unsigned short)f2bf(acc[m][n][q]);
      }
    }
  }
}

// ---------------- GEMM1: 128-row tiles (straggler fix), glds staging ---------
__global__ __launch_bounds__(256, 2) void gemm1_k(
    const void* __restrict__ Ap, const unsigned short* __restrict__ Bimg,
    unsigned short* __restrict__ ybl, unsigned short* __restrict__ ybr,
    int N, int nsteps){
  __shared__ char AsB[128*128];                 // 16 KB
  __shared__ char BsB[36864];                   // 36 KB
  const int tid = threadIdx.x;
  const int c0  = blockIdx.x * 128;
  const int l   = tid & 63, wid = tid >> 6;
  const int nw  = wid * 64;
  const int lr  = l & 15, lq = l >> 4;

  f32x4 acc[8][4];
  #pragma unroll
  for (int m=0;m<8;++m)
    #pragma unroll
    for (int n=0;n<4;++n) acc[m][n] = (f32x4){0.f,0.f,0.f,0.f};

  const char* h1b = (const char*)Ap;

  for (int s = 0; s < nsteps; ++s){
    if (s) __syncthreads();
    {
      const char* bsrc = (const char*)Bimg + (size_t)s*36864;
      #pragma unroll
      for (int i = 0; i < 9; ++i){
        int chunk = i*256 + tid;
        glds16(bsrc + (size_t)chunk*16, &BsB[(i*256 + wid*64)*16]);
      }
    }
    #pragma unroll
    for (int i = 0; i < 4; ++i){                // 128 rows x 128B per step
      int chunk = i*256 + tid;
      int row = chunk >> 3, cb = (chunk & 7)*16;
      glds16(h1b + (size_t)(c0 + row)*256 + s*128 + cb,
             &AsB[(i*256 + wid*64)*16]);
    }
    __syncthreads();                            // glds -> full drain required
    #pragma unroll
    for (int ks = 0; ks < 2; ++ks){
      bf16x8 a[8];
      #pragma unroll
      for (int m = 0; m < 8; ++m){
        int row = m*16 + lr;
        int colb = (ks*64 + lq*16) ^ ((row & 7) << 4);
        a[m] = *(const bf16x8*)&AsB[row*128 + colb];
      }
      #pragma unroll
      for (int n = 0; n < 4; ++n){
        bf16x8 b = *(const bf16x8*)&BsB[(nw + n*16 + lr)*144 + ks*64 + lq*16];
        #pragma unroll
        for (int m = 0; m < 8; ++m)
          acc[m][n] = __builtin_amdgcn_mfma_f32_16x16x32_bf16(a[m], b, acc[m][n], 0, 0, 0);
      }
    }
  }
  unsigned short* op  = (nw < 128) ? ybl : ybr;
  const int       nc  = (nw < 128) ? nw : nw - 128;
  #pragma unroll
  for (int m = 0; m < 8; ++m){
    int rbase = c0 + m*16 + lq*4;
    #pragma unroll
    for (int q = 0; q < 4; ++q){
      int r = rbase + q;
      if (r < N){
        #pragma unroll
        for (int n = 0; n < 4; ++n)
          op[(size_t)r*128 + nc + n*16 + lr] = (unsigned short)f2bf(acc[m][n][q]);
      }
    }
  }
}

// ------- aggregate: lane-parallel col fetch + 16-deep row gather -------------
template<int LAYER>
__global__ void aggregate_k(const unsigned short* __restrict__ ybl,
    const unsigned short* __restrict__ ybr,
    const int* __restrict__ rowp, const int* __restrict__ bsum,
    const int* __restrict__ col,
    const float* __restrict__ inv, const float* __restrict__ bias,
    void* __restrict__ outp, int N){
  int node = blockIdx.x*4 + (threadIdx.x >> 6);
  int l = threadIdx.x & 63;
  if (node >= N) return;
  int b = rowp[node]   + bsum[node >> 8];
  int e = rowp[node+1] + bsum[(node+1) >> 8];
  int f2 = l*2;
  const unsigned* yl = (const unsigned*)ybl;
  float s0=0.f,s1=0.f,t0=0.f,t1=0.f,u0=0.f,u1=0.f,w0=0.f,w1=0.f;
  for (int kb = b; kb < e; kb += 64){
    int rem = e - kb; if (rem > 64) rem = 64;
    int myc = (l < rem) ? col[kb + l] : 0;      // one coalesced col load
    for (int j = 0; j < rem; j += 16){
      unsigned a[16];
      #pragma unroll
      for (int jj = 0; jj < 16; ++jj){
        int src = __shfl(myc, j + jj);          // broadcast (VALU/LDS, cheap)
        unsigned v = yl[(size_t)src*64 + l];    // gather, 16 in flight
        a[jj] = (j + jj < rem) ? v : 0u;
      }
      #pragma unroll
      for (int h = 0; h < 2; ++h){
        s0 += bl(a[h*8+0]); s1 += bh(a[h*8+0]); t0 += bl(a[h*8+1]); t1 += bh(a[h*8+1]);
        u0 += bl(a[h*8+2]); u1 += bh(a[h*8+2]); w0 += bl(a[h*8+3]); w1 += bh(a[h*8+3]);
        s0 += bl(a[h*8+4]); s1 += bh(a[h*8+4]); t0 += bl(a[h*8+5]); t1 += bh(a[h*8+5]);
        u0 += bl(a[h*8+6]); u1 += bh(a[h*8+6]); w0 += bl(a[h*8+7]); w1 += bh(a[h*8+7]);
      }
    }
  }
  s0 = (s0 + t0) + (u0 + w0);
  s1 = (s1 + t1) + (u1 + w1);
  unsigned vs = *(const unsigned*)&ybr[(size_t)node*128 + f2];
  float iv = inv[node];
  float r0 = s0*iv + bias[f2]   + bl(vs);
  float r1 = s1*iv + bias[f2+1] + bh(vs);
  r0 = (r0 > 0.f) ? r0 : expm1f(r0);
  r1 = (r1 > 0.f) ? r1 : expm1f(r1);
  if (LAYER == 0){
    int sf = f2 >> 6, fo = f2 & 63, g = fo >> 3;
    size_t byte = (size_t)node*256 + (size_t)(sf*128 + ((g ^ (node & 7)) << 4) + (fo & 7)*2);
    *(unsigned*)((char*)outp + byte) = f2bf(r0) | (f2bf(r1) << 16);
  } else {
    *(float2*)((float*)outp + (size_t)node*128 + f2) = make_float2(r0, r1);
  }
}

static inline size_t align_up(size_t v, size_t a){ return (v + a - 1) & ~(a - 1); }

extern "C" void kernel_launch(void* const* d_in, const int* in_sizes, int n_in,
                              void* d_out, int out_size, void* d_ws, size_t ws_size,
                              hipStream_t stream) {
  const float* x   = (const float*)d_in[0];
  const int*   ei  = (const int*)d_in[1];      // harness delivers int32
  const float* Wl0 = (const float*)d_in[2];
  const float* bl0 = (const float*)d_in[3];
  const float* Wr0 = (const float*)d_in[4];
  const float* Wl1 = (const float*)d_in[5];
  const float* bl1 = (const float*)d_in[6];
  const float* Wr1 = (const float*)d_in[7];

  int N = in_sizes[0] / IN_DIM;   // 50000
  int E = in_sizes[1] / 2;        // 800000

  const int NS0 = 16;             // K padded to 1024
  const int NS1 = 2;              // K = 128
  int nsb = (N + 255) / 256;      // 196 (<=256 for inline bsum scan)

  char* base = (char*)d_ws;
  size_t off = 0;
  unsigned short* ybl = (unsigned short*)(base + off); off = align_up(off + (size_t)N*128*2, 256);
  unsigned short* ybr = (unsigned short*)(base + off); off = align_up(off + (size_t)N*128*2, 256);
  float* inv  = (float*)(base + off); off = align_up(off + (size_t)N*4, 256);
  int*   cnt  = (int*)  (base + off); off = align_up(off + (size_t)N*8 + 256, 256); // cnt+pos+ticket
  int*   pos  = cnt + N;
  int*   ticket = cnt + 2*N;
  int*   rowp = (int*)  (base + off); off = align_up(off + (size_t)(N+1)*4, 256);
  int*   bsum = (int*)  (base + off); off = align_up(off + (size_t)(nsb+1)*4, 256);
  int*   col  = (int*)  (base + off); off = align_up(off + (size_t)E*4, 256);
  unsigned short* B0img = (unsigned short*)(base + off); off = align_up(off + (size_t)524288*2, 256);
  unsigned short* B1img = (unsigned short*)(base + off); off = align_up(off + (size_t)NS1*18432*2, 256);
  void* h1b = d_out;              // bf16 swizzled h1 (12.8 MB) inside d_out
  (void)ws_size; (void)n_in; (void)out_size;

  int t0n = 524288, t1n = NS1*18432;
  int zn  = 2*N + 64;             // cnt + pos + ticket (+pad), zeroed by prep_k
  prep_k<<<(t0n+t1n+zn+255)/256, 256, 0, stream>>>(Wl0, Wr0, Wl1, Wr1,
                                                   B0img, B1img, t0n, t1n,
                                                   cnt, zn);

  int nblk0 = (N + 255) / 256;    // 196 gemm0 tiles (256 cells each)
  int cblk  = (E + 511) / 512;    // 1563 count blocks (512 threads each)
  int nblk1 = (N + 127) / 128;    // 391 gemm1 tiles
  int ablk  = (N + 3) / 4;        // 12500

  // gemm0 + edge-count in one dispatch; counts are tail bids (backfill overlap)
  gemm0_count_k<<<nblk0 + cblk, 512, 0, stream>>>(x, B0img, ybl, ybr, N, IN_DIM,
                                                  NS0, nblk0, ei, E, cnt);
  scan1_k<<<nsb, 256, 0, stream>>>(cnt, rowp, inv, bsum, ticket, N, nsb);
  fill_col_k<<<(E+255)/256, 256, 0, stream>>>(ei, E, rowp, bsum, pos, col);
  aggregate_k<0><<<ablk, 256, 0, stream>>>(ybl, ybr, rowp, bsum, col, inv, bl0, h1b, N);

  // layer 1 (ybl/ybr reused; agg0 fully drained first; 128-row tiles)
  gemm1_k<<<nblk1, 256, 0, stream>>>(h1b, B1img, ybl, ybr, N, NS1);
  aggregate_k<1><<<ablk, 256, 0, stream>>>(ybl, ybr, rowp, bsum, col, inv, bl1, d_out, N);
}

// Round 15
// 203.572 us; speedup vs baseline: 1.2634x; 1.0221x over previous
//
#include <hip/hip_runtime.h>
#include <hip/hip_bf16.h>

// GraphSAGE 2-layer forward: project-then-aggregate, bf16-MFMA GEMMs.
// Round 25: combine r14's B-dedup with r12's 2-blocks/CU co-residency —
// never yet tested together (r14's 100KB BsB ping-pong forced 1 block/CU and
// ALSO evicted count blocks, since they share the kernel's static LDS).
// gemm0: 128-cell x 256-out tiles, 256 threads (r11 shape), B glds-staged
// into a SINGLE 32KB BsB (kills the 4-way per-wave B duplication: 64->32KB
// per step), AsB 18KB (144-pad) -> LDS 50KB -> 2 blocks/CU; regs ~193 ->
// 2 waves/SIMD consistent. Single-buffer hazard solved by ORDER, not buffers:
//   stageB(s); packx (consumes xv(s));
//   __syncthreads (full drain — only B(s) outstanding, xv already consumed);
//   loadx(s+1) (issued AFTER the drain -> never force-drained, flies across
//   domfma + next lgkm-only KBARRIER); domfma.
// 391 blocks <= 512 slots, single round; count blocks co-reside again.
// Everything else frozen at r14. 7 dispatches.

#define IN_DIM 1000

#define KBARRIER() asm volatile("s_waitcnt lgkmcnt(0)\n\ts_barrier" ::: "memory")

typedef __attribute__((ext_vector_type(8))) short bf16x8;
typedef __attribute__((ext_vector_type(4))) float f32x4;

static __device__ __forceinline__ unsigned int f2bf(float f){
  union { float f; unsigned int u; } v; v.f = f;
  return (v.u + 0x7fffu + ((v.u >> 16) & 1u)) >> 16;   // RNE
}
static __device__ __forceinline__ float bl(unsigned v){
  union { unsigned u; float f; } t; t.u = v << 16; return t.f;
}
static __device__ __forceinline__ float bh(unsigned v){
  union { unsigned u; float f; } t; t.u = v & 0xFFFF0000u; return t.f;
}
static __device__ __forceinline__ void glds16(const void* g, void* lds){
  __builtin_amdgcn_global_load_lds(
      (const __attribute__((address_space(1))) unsigned int*)g,
      (__attribute__((address_space(3))) unsigned int*)lds, 16, 0, 0);
}

// -------- prep: B0img (fragment layout) + B1img (row layout) + zeroing -------
__global__ void prep_k(const float* __restrict__ Wl0, const float* __restrict__ Wr0,
                       const float* __restrict__ Wl1, const float* __restrict__ Wr1,
                       unsigned short* __restrict__ img0,
                       unsigned short* __restrict__ img1, int total0, int total1,
                       int* __restrict__ zptr, int zn){
  int idx = blockIdx.x*256 + threadIdx.x;
  if (idx < total0){
    int j  = idx & 7;
    int l  = (idx >> 3) & 63;
    int ks = (idx >> 9) & 1;
    int n  = (idx >> 10) & 3;
    int w  = (idx >> 12) & 3;
    int s  = idx >> 14;
    int row = w*64 + n*16 + (l & 15);
    int k   = s*64 + ks*32 + (l >> 4)*8 + j;
    float val = 0.f;
    if (k < IN_DIM)
      val = (row < 128) ? Wl0[(size_t)row*IN_DIM + k] : Wr0[(size_t)(row-128)*IN_DIM + k];
    img0[idx] = (unsigned short)f2bf(val);
    return;
  }
  idx -= total0;
  if (idx < total1){
    int s   = idx / (256*72);
    int rem = idx % (256*72);
    int n   = rem / 72;
    int e   = rem % 72;
    float val = 0.f;
    if (e < 64){
      int k = s*64 + e;
      if (k < 128) val = (n < 128) ? Wl1[(size_t)n*128 + k] : Wr1[(size_t)(n-128)*128 + k];
    }
    img1[idx] = (unsigned short)f2bf(val);
    return;
  }
  idx -= total1;
  if (idx < zn) zptr[idx] = 0;
}

// -------- scan1: block-local excl prescan + inv; last block scans bsum ------
__global__ void scan1_k(const int* __restrict__ cnt, int* __restrict__ rowp,
                        float* __restrict__ inv, int* __restrict__ bsum,
                        int* __restrict__ ticket, int N, int nb){
  __shared__ int wt[4];
  __shared__ int lastS;
  int bid = blockIdx.x;
  int i = bid*256 + threadIdx.x;
  int lane = threadIdx.x & 63, wid = threadIdx.x >> 6;
  int v = (i < N) ? cnt[i] : 0;
  int sc = v;
  #pragma unroll
  for (int off = 1; off < 64; off <<= 1){
    int o = __shfl_up(sc, off);
    if (lane >= off) sc += o;
  }
  if (lane == 63) wt[wid] = sc;
  __syncthreads();
  if (threadIdx.x == 0){
    int a = 0;
    #pragma unroll
    for (int j = 0; j < 4; ++j){ int t = wt[j]; wt[j] = a; a += t; }
    bsum[bid] = a;
    if (bid == nb-1 && (N & 255)) rowp[N] = a;
  }
  __syncthreads();
  if (i < N){
    rowp[i] = wt[wid] + sc - v;
    inv[i]  = 1.0f / fmaxf((float)v, 1.0f);
  }
  __threadfence();
  if (threadIdx.x == 0){
    int t = __hip_atomic_fetch_add(ticket, 1, __ATOMIC_ACQ_REL, __HIP_MEMORY_SCOPE_AGENT);
    lastS = (t == (int)gridDim.x - 1);
  }
  __syncthreads();
  if (lastS){
    __threadfence();
    int t2 = threadIdx.x;
    int bv = (t2 < nb) ? __hip_atomic_load(&bsum[t2], __ATOMIC_RELAXED,
                                           __HIP_MEMORY_SCOPE_AGENT) : 0;
    int sc2 = bv;
    #pragma unroll
    for (int off = 1; off < 64; off <<= 1){
      int o = __shfl_up(sc2, off);
      if (lane >= off) sc2 += o;
    }
    __syncthreads();
    if (lane == 63) wt[wid] = sc2;
    __syncthreads();
    if (t2 == 0){
      int a = 0;
      #pragma unroll
      for (int j = 0; j < 4; ++j){ int t = wt[j]; wt[j] = a; a += t; }
      bsum[nb] = a;
      if (!(N & 255)) rowp[N] = 0;
    }
    __syncthreads();
    if (t2 < nb) bsum[t2] = wt[wid] + sc2 - bv;
  }
}

__global__ void fill_col_k(const int* __restrict__ ei, int E,
                           const int* __restrict__ rowp, const int* __restrict__ bsum,
                           int* __restrict__ pos, int* __restrict__ col){
  int e = blockIdx.x*blockDim.x + threadIdx.x;
  if (e < E){
    int src = ei[e];
    int dst = ei[(size_t)E + e];
    int p = atomicAdd(&pos[dst], 1);
    col[rowp[dst] + bsum[dst >> 8] + p] = src;
  }
}

// ------- GEMM0: 128-cell tiles, 256 thr, LDS-staged B (single buf) + count ---
// bid < nblk: gemm tile (128 cells x 256 outputs). LDS 50KB -> 2 blocks/CU;
// 391 blocks <= 512 slots (single round); count blocks co-reside.
// Schedule per step: KBARRIER(lgkm) | stageB(s) glds | packx (waits xv(s)) |
// __syncthreads (full drain: only B(s) outstanding) | loadx(s+1) | domfma.
__global__ __launch_bounds__(256, 2) void gemm0_count_k(
    const float* __restrict__ x, const unsigned short* __restrict__ B0img,
    unsigned short* __restrict__ ybl, unsigned short* __restrict__ ybr,
    int N, int Ka, int nsteps, int nblk,
    const int* __restrict__ ei, int E, int* __restrict__ cnt){
  if ((int)blockIdx.x >= nblk){                 // tail: edge counting
    int idx = ((int)blockIdx.x - nblk)*256 + threadIdx.x;
    if (idx < E) atomicAdd(&cnt[ei[(size_t)E + idx]], 1);
    return;
  }
  __shared__ char AsB[128*144];                 // 18 KB: 128 cells x 64 k bf16
  __shared__ char BsB[32768];                   // 32 KB: B(s), single buffer
  const int tid = threadIdx.x;
  const int c0  = blockIdx.x * 128;
  const int l   = tid & 63, wid = tid >> 6;     // 4 waves = 4 n-quadrants
  const int nw  = wid * 64;
  const int lr  = l & 15, lq = l >> 4;
  const int c4  = (tid & 31)*4;                 // 4 cells per thread
  const int kg  = tid >> 5;                     // 8 k-groups x 8 k
  const int ce  = c0 + c4;
  const int ceff = (ce < N) ? ce : 0;           // N%4==0 -> ce<N covers ce..ce+3

  f32x4 acc[8][4];
  #pragma unroll
  for (int m=0;m<8;++m)
    #pragma unroll
    for (int n=0;n<4;++n) acc[m][n] = (f32x4){0.f,0.f,0.f,0.f};

  float2 xv0[8], xv1[8];                        // cells ce+0/1 and ce+2/3

  auto loadx = [&](int step){
    #pragma unroll
    for (int kk = 0; kk < 8; ++kk){
      int k = step*64 + kg*8 + kk;
      k = (k < Ka) ? k : (Ka - 1);              // B zero-pads k>=Ka
      const float* p = &x[(size_t)k*N + ceff];
      xv0[kk] = *(const float2*)p;
      xv1[kk] = *(const float2*)(p + 2);
    }
  };
  auto stageB = [&](int s){
    const char* src = (const char*)B0img + (size_t)s*32768;
    #pragma unroll
    for (int i = 0; i < 8; ++i){                // 2048 granules / 256 thr
      int base = i*256 + wid*64;                // wave-uniform granule base
      glds16(src + (size_t)(base + l)*16, &BsB[base*16]);
    }
  };
  auto packx = [&](){
    unsigned w0[4], w1[4], w2[4], w3[4];
    #pragma unroll
    for (int j = 0; j < 4; ++j){
      asm("v_cvt_pk_bf16_f32 %0, %1, %2" : "=v"(w0[j]) : "v"(xv0[2*j].x), "v"(xv0[2*j+1].x));
      asm("v_cvt_pk_bf16_f32 %0, %1, %2" : "=v"(w1[j]) : "v"(xv0[2*j].y), "v"(xv0[2*j+1].y));
      asm("v_cvt_pk_bf16_f32 %0, %1, %2" : "=v"(w2[j]) : "v"(xv1[2*j].x), "v"(xv1[2*j+1].x));
      asm("v_cvt_pk_bf16_f32 %0, %1, %2" : "=v"(w3[j]) : "v"(xv1[2*j].y), "v"(xv1[2*j+1].y));
    }
    *(uint4*)&AsB[(c4+0)*144 + kg*16] = make_uint4(w0[0],w0[1],w0[2],w0[3]);
    *(uint4*)&AsB[(c4+1)*144 + kg*16] = make_uint4(w1[0],w1[1],w1[2],w1[3]);
    *(uint4*)&AsB[(c4+2)*144 + kg*16] = make_uint4(w2[0],w2[1],w2[2],w2[3]);
    *(uint4*)&AsB[(c4+3)*144 + kg*16] = make_uint4(w3[0],w3[1],w3[2],w3[3]);
  };
  auto domfma = [&](){
    #pragma unroll
    for (int ks = 0; ks < 2; ++ks){
      bf16x8 a[8];
      #pragma unroll
      for (int m = 0; m < 8; ++m)
        a[m] = *(const bf16x8*)&AsB[(m*16 + lr)*144 + ks*64 + lq*16];
      #pragma unroll
      for (int n = 0; n < 4; ++n){
        bf16x8 b = *(const bf16x8*)&BsB[wid*8192 + (n*2+ks)*1024 + l*16];
        #pragma unroll
        for (int m = 0; m < 8; ++m)
          acc[m][n] = __builtin_amdgcn_mfma_f32_16x16x32_bf16(a[m], b, acc[m][n], 0, 0, 0);
      }
    }
  };

  loadx(0);
  for (int s = 0; s < nsteps; ++s){
    if (s) KBARRIER();                 // lgkm-only: AsB/BsB reads of s-1 done
    stageB(s);                         // glds 32KB; lands by the full drain
    packx();                           // waits xv(s); cvt; ds_write AsB
    __syncthreads();                   // full drain: ONLY B(s) outstanding
    if (s + 1 < nsteps) loadx(s + 1);  // issued after drain -> never drained;
    domfma();                          // flies across domfma + next KBARRIER
  }

  unsigned short* op = (nw < 128) ? ybl : ybr;
  const int       nc = (nw < 128) ? nw : nw - 128;
  #pragma unroll
  for (int m = 0; m < 8; ++m){
    int rbase = c0 + m*16 + lq*4;
    #pragma unroll
    for (int q = 0; q < 4; ++q){
      int r2 = rbase + q;
      if (r2 < N){
        #pragma unroll
        for (int n = 0; n < 4; ++n)
          op[(size_t)r2*128 + nc + n*16 + lr] = (unsigned short)f2bf(acc[m][n][q]);
      }
    }
  }
}

// ---------------- GEMM1: 128-row tiles (straggler fix), glds staging ---------
__global__ __launch_bounds__(256, 2) void gemm1_k(
    const void* __restrict__ Ap, const unsigned short* __restrict__ Bimg,
    unsigned short* __restrict__ ybl, unsigned short* __restrict__ ybr,
    int N, int nsteps){
  __shared__ char AsB[128*128];                 // 16 KB
  __shared__ char BsB[36864];                   // 36 KB
  const int tid = threadIdx.x;
  const int c0  = blockIdx.x * 128;
  const int l   = tid & 63, wid = tid >> 6;
  const int nw  = wid * 64;
  const int lr  = l & 15, lq = l >> 4;

  f32x4 acc[8][4];
  #pragma unroll
  for (int m=0;m<8;++m)
    #pragma unroll
    for (int n=0;n<4;++n) acc[m][n] = (f32x4){0.f,0.f,0.f,0.f};

  const char* h1b = (const char*)Ap;

  for (int s = 0; s < nsteps; ++s){
    if (s) __syncthreads();
    {
      const char* bsrc = (const char*)Bimg + (size_t)s*36864;
      #pragma unroll
      for (int i = 0; i < 9; ++i){
        int chunk = i*256 + tid;
        glds16(bsrc + (size_t)chunk*16, &BsB[(i*256 + wid*64)*16]);
      }
    }
    #pragma unroll
    for (int i = 0; i < 4; ++i){                // 128 rows x 128B per step
      int chunk = i*256 + tid;
      int row = chunk >> 3, cb = (chunk & 7)*16;
      glds16(h1b + (size_t)(c0 + row)*256 + s*128 + cb,
             &AsB[(i*256 + wid*64)*16]);
    }
    __syncthreads();                            // glds -> full drain required
    #pragma unroll
    for (int ks = 0; ks < 2; ++ks){
      bf16x8 a[8];
      #pragma unroll
      for (int m = 0; m < 8; ++m){
        int row = m*16 + lr;
        int colb = (ks*64 + lq*16) ^ ((row & 7) << 4);
        a[m] = *(const bf16x8*)&AsB[row*128 + colb];
      }
      #pragma unroll
      for (int n = 0; n < 4; ++n){
        bf16x8 b = *(const bf16x8*)&BsB[(nw + n*16 + lr)*144 + ks*64 + lq*16];
        #pragma unroll
        for (int m = 0; m < 8; ++m)
          acc[m][n] = __builtin_amdgcn_mfma_f32_16x16x32_bf16(a[m], b, acc[m][n], 0, 0, 0);
      }
    }
  }
  unsigned short* op  = (nw < 128) ? ybl : ybr;
  const int       nc  = (nw < 128) ? nw : nw - 128;
  #pragma unroll
  for (int m = 0; m < 8; ++m){
    int rbase = c0 + m*16 + lq*4;
    #pragma unroll
    for (int q = 0; q < 4; ++q){
      int r = rbase + q;
      if (r < N){
        #pragma unroll
        for (int n = 0; n < 4; ++n)
          op[(size_t)r*128 + nc + n*16 + lr] = (unsigned short)f2bf(acc[m][n][q]);
      }
    }
  }
}

// ------- aggregate: lane-parallel col fetch + 16-deep row gather -------------
template<int LAYER>
__global__ void aggregate_k(const unsigned short* __restrict__ ybl,
    const unsigned short* __restrict__ ybr,
    const int* __restrict__ rowp, const int* __restrict__ bsum,
    const int* __restrict__ col,
    const float* __restrict__ inv, const float* __restrict__ bias,
    void* __restrict__ outp, int N){
  int node = blockIdx.x*4 + (threadIdx.x >> 6);
  int l = threadIdx.x & 63;
  if (node >= N) return;
  int b = rowp[node]   + bsum[node >> 8];
  int e = rowp[node+1] + bsum[(node+1) >> 8];
  int f2 = l*2;
  const unsigned* yl = (const unsigned*)ybl;
  float s0=0.f,s1=0.f,t0=0.f,t1=0.f,u0=0.f,u1=0.f,w0=0.f,w1=0.f;
  for (int kb = b; kb < e; kb += 64){
    int rem = e - kb; if (rem > 64) rem = 64;
    int myc = (l < rem) ? col[kb + l] : 0;      // one coalesced col load
    for (int j = 0; j < rem; j += 16){
      unsigned a[16];
      #pragma unroll
      for (int jj = 0; jj < 16; ++jj){
        int src = __shfl(myc, j + jj);          // broadcast (VALU/LDS, cheap)
        unsigned v = yl[(size_t)src*64 + l];    // gather, 16 in flight
        a[jj] = (j + jj < rem) ? v : 0u;
      }
      #pragma unroll
      for (int h = 0; h < 2; ++h){
        s0 += bl(a[h*8+0]); s1 += bh(a[h*8+0]); t0 += bl(a[h*8+1]); t1 += bh(a[h*8+1]);
        u0 += bl(a[h*8+2]); u1 += bh(a[h*8+2]); w0 += bl(a[h*8+3]); w1 += bh(a[h*8+3]);
        s0 += bl(a[h*8+4]); s1 += bh(a[h*8+4]); t0 += bl(a[h*8+5]); t1 += bh(a[h*8+5]);
        u0 += bl(a[h*8+6]); u1 += bh(a[h*8+6]); w0 += bl(a[h*8+7]); w1 += bh(a[h*8+7]);
      }
    }
  }
  s0 = (s0 + t0) + (u0 + w0);
  s1 = (s1 + t1) + (u1 + w1);
  unsigned vs = *(const unsigned*)&ybr[(size_t)node*128 + f2];
  float iv = inv[node];
  float r0 = s0*iv + bias[f2]   + bl(vs);
  float r1 = s1*iv + bias[f2+1] + bh(vs);
  r0 = (r0 > 0.f) ? r0 : expm1f(r0);
  r1 = (r1 > 0.f) ? r1 : expm1f(r1);
  if (LAYER == 0){
    int sf = f2 >> 6, fo = f2 & 63, g = fo >> 3;
    size_t byte = (size_t)node*256 + (size_t)(sf*128 + ((g ^ (node & 7)) << 4) + (fo & 7)*2);
    *(unsigned*)((char*)outp + byte) = f2bf(r0) | (f2bf(r1) << 16);
  } else {
    *(float2*)((float*)outp + (size_t)node*128 + f2) = make_float2(r0, r1);
  }
}

static inline size_t align_up(size_t v, size_t a){ return (v + a - 1) & ~(a - 1); }

extern "C" void kernel_launch(void* const* d_in, const int* in_sizes, int n_in,
                              void* d_out, int out_size, void* d_ws, size_t ws_size,
                              hipStream_t stream) {
  const float* x   = (const float*)d_in[0];
  const int*   ei  = (const int*)d_in[1];      // harness delivers int32
  const float* Wl0 = (const float*)d_in[2];
  const float* bl0 = (const float*)d_in[3];
  const float* Wr0 = (const float*)d_in[4];
  const float* Wl1 = (const float*)d_in[5];
  const float* bl1 = (const float*)d_in[6];
  const float* Wr1 = (const float*)d_in[7];

  int N = in_sizes[0] / IN_DIM;   // 50000
  int E = in_sizes[1] / 2;        // 800000

  const int NS0 = 16;             // K padded to 1024
  const int NS1 = 2;              // K = 128
  int nsb = (N + 255) / 256;      // 196 (<=256 for inline bsum scan)

  char* base = (char*)d_ws;
  size_t off = 0;
  unsigned short* ybl = (unsigned short*)(base + off); off = align_up(off + (size_t)N*128*2, 256);
  unsigned short* ybr = (unsigned short*)(base + off); off = align_up(off + (size_t)N*128*2, 256);
  float* inv  = (float*)(base + off); off = align_up(off + (size_t)N*4, 256);
  int*   cnt  = (int*)  (base + off); off = align_up(off + (size_t)N*8 + 256, 256); // cnt+pos+ticket
  int*   pos  = cnt + N;
  int*   ticket = cnt + 2*N;
  int*   rowp = (int*)  (base + off); off = align_up(off + (size_t)(N+1)*4, 256);
  int*   bsum = (int*)  (base + off); off = align_up(off + (size_t)(nsb+1)*4, 256);
  int*   col  = (int*)  (base + off); off = align_up(off + (size_t)E*4, 256);
  unsigned short* B0img = (unsigned short*)(base + off); off = align_up(off + (size_t)524288*2, 256);
  unsigned short* B1img = (unsigned short*)(base + off); off = align_up(off + (size_t)NS1*18432*2, 256);
  void* h1b = d_out;              // bf16 swizzled h1 (12.8 MB) inside d_out
  (void)ws_size; (void)n_in; (void)out_size;

  int t0n = 524288, t1n = NS1*18432;
  int zn  = 2*N + 64;             // cnt + pos + ticket (+pad), zeroed by prep_k
  prep_k<<<(t0n+t1n+zn+255)/256, 256, 0, stream>>>(Wl0, Wr0, Wl1, Wr1,
                                                   B0img, B1img, t0n, t1n,
                                                   cnt, zn);

  int nblk = (N + 127) / 128;     // 391 gemm0 tiles (128 cells each)
  int cblk = (E + 255) / 256;     // 3125
  int ablk = (N + 3) / 4;         // 12500

  // gemm0 + edge-count in one dispatch; counts are tail bids (backfill overlap)
  gemm0_count_k<<<nblk + cblk, 256, 0, stream>>>(x, B0img, ybl, ybr, N, IN_DIM,
                                                 NS0, nblk, ei, E, cnt);
  scan1_k<<<nsb, 256, 0, stream>>>(cnt, rowp, inv, bsum, ticket, N, nsb);
  fill_col_k<<<(E+255)/256, 256, 0, stream>>>(ei, E, rowp, bsum, pos, col);
  aggregate_k<0><<<ablk, 256, 0, stream>>>(ybl, ybr, rowp, bsum, col, inv, bl0, h1b, N);

  // layer 1 (ybl/ybr reused; agg0 fully drained first; 128-row tiles)
  gemm1_k<<<nblk, 256, 0, stream>>>(h1b, B1img, ybl, ybr, N, NS1);
  aggregate_k<1><<<ablk, 256, 0, stream>>>(ybl, ybr, rowp, bsum, col, inv, bl1, d_out, N);
}